// Round 1
// baseline (17.854 us; speedup 1.0000x reference)
//
#include <hip/hip_runtime.h>

// DuplicateByDuration: y[b,c,j] = x[b,c,i(b,j)] * x_mask[b,i] * y_mask[b,j]
// where i(b,j) is the text token whose cumulative-duration interval contains j.
// B=16, C=192, T_TEXT=512, T_FEAT=2048, w in [0,8).

#define BB 16
#define CC 192
#define T_TEXT 512
#define T_FEAT 2048

// Kernel A: per batch, scan durations and build idx/scale maps.
// grid = B blocks, 512 threads (one per text token).
__global__ __launch_bounds__(512) void build_idx_kernel(
    const int* __restrict__ w, const float* __restrict__ x_mask,
    const float* __restrict__ y_mask, int* __restrict__ idx,
    float* __restrict__ scale)
{
    const int b = blockIdx.x;
    const int i = threadIdx.x;  // 0..511

    __shared__ int s[T_TEXT];

    const float wf = (float)w[b * T_TEXT + i];
    const float xm = x_mask[b * T_TEXT + i];
    // reference: wm = (w.astype(f32) * x_mask).astype(i32)  (truncation)
    int wm = (int)(wf * xm);
    s[i] = wm;

    // Hillis-Steele inclusive scan over 512 elements in LDS
    for (int off = 1; off < T_TEXT; off <<= 1) {
        __syncthreads();
        int v = (i >= off) ? s[i - off] : 0;
        __syncthreads();
        s[i] += v;
    }
    __syncthreads();

    // init: frames default to idx=0, scale=0 (branch-free zero in gather)
    for (int j = i; j < T_FEAT; j += T_TEXT) {
        idx[b * T_FEAT + j] = 0;
        scale[b * T_FEAT + j] = 0.0f;
    }
    __syncthreads();  // order init writes before scatter writes (block-level fence)

    int start = (i > 0) ? s[i - 1] : 0;
    int end = s[i];
    if (start > T_FEAT) start = T_FEAT;
    if (end > T_FEAT) end = T_FEAT;
    for (int j = start; j < end; ++j) {
        idx[b * T_FEAT + j] = i;
        scale[b * T_FEAT + j] = xm * y_mask[b * T_FEAT + j];
    }
}

// Kernel B: branch-free vectorized gather.
// One float4 of output per thread; total B*C*T_FEAT/4 threads.
__global__ __launch_bounds__(256) void gather_kernel(
    const float* __restrict__ x, const int* __restrict__ idx,
    const float* __restrict__ scale, float* __restrict__ out)
{
    const int t = blockIdx.x * blockDim.x + threadIdx.x;
    const int base = t * 4;                 // flat output index (b*C + c)*T_FEAT + j
    const int bc = base / T_FEAT;           // b*C + c
    const int j = base - bc * T_FEAT;       // multiple of 4, stays in-row
    const int b = bc / CC;

    const int4 i4 = *(const int4*)(idx + b * T_FEAT + j);
    const float4 s4 = *(const float4*)(scale + b * T_FEAT + j);
    const float* __restrict__ xrow = x + bc * T_TEXT;

    float4 o;
    o.x = xrow[i4.x] * s4.x;
    o.y = xrow[i4.y] * s4.y;
    o.z = xrow[i4.z] * s4.z;
    o.w = xrow[i4.w] * s4.w;
    *(float4*)(out + base) = o;
}

extern "C" void kernel_launch(void* const* d_in, const int* in_sizes, int n_in,
                              void* d_out, int out_size, void* d_ws, size_t ws_size,
                              hipStream_t stream) {
    const float* x      = (const float*)d_in[0];
    const int*   w      = (const int*)d_in[1];
    const float* x_mask = (const float*)d_in[2];
    const float* y_mask = (const float*)d_in[3];
    float* out = (float*)d_out;

    // ws layout: [B*T_FEAT int idx][B*T_FEAT float scale] = 256 KB
    int*   idx   = (int*)d_ws;
    float* scale = (float*)((char*)d_ws + (size_t)BB * T_FEAT * sizeof(int));

    build_idx_kernel<<<BB, T_TEXT, 0, stream>>>(w, x_mask, y_mask, idx, scale);

    const int total4 = BB * CC * T_FEAT / 4;       // 1,572,864 threads
    gather_kernel<<<total4 / 256, 256, 0, stream>>>(x, idx, scale, out);
}

// Round 2
// 15.676 us; speedup vs baseline: 1.1389x; 1.1389x over previous
//
#include <hip/hip_runtime.h>

// DuplicateByDuration, fused single kernel.
// y[b,c,j] = x[b,c,i(b,j)] * x_mask[b,i] * y_mask[b,j], where i(b,j) is the
// token whose cum-duration interval contains frame j; 0 past total duration.
// B=16, C=192, T_TEXT=512, T_FEAT=2048, w in [0,8).
//
// Each block: redundantly scan its batch's durations in LDS (cheap), build the
// frame->token inverse map + scale in LDS, then stream CH_TILE channels out.

#define BB 16
#define CC 192
#define T_TEXT 512
#define T_FEAT 2048
#define CH_TILE 3
#define NTILES (CC / CH_TILE)   // 64
#define NTHREADS 256

__global__ __launch_bounds__(NTHREADS) void dup_by_dur_fused(
    const float* __restrict__ x, const int* __restrict__ w,
    const float* __restrict__ x_mask, const float* __restrict__ y_mask,
    float* __restrict__ out)
{
    const int t    = threadIdx.x;
    const int b    = blockIdx.x / NTILES;
    const int tile = blockIdx.x % NTILES;

    __shared__ int   swm[T_TEXT];     // masked durations
    __shared__ float sxm[T_TEXT];     // x_mask per token
    __shared__ int   sp[NTHREADS];    // pairwise-sum scan buffer
    __shared__ short sidx[T_FEAT];    // frame -> token
    __shared__ float sscale[T_FEAT];  // x_mask[i] * y_mask[j] (0 if invalid)

    // --- load durations + x_mask (2 tokens/thread) ---
    for (int i = t; i < T_TEXT; i += NTHREADS) {
        float wf = (float)w[b * T_TEXT + i];
        float xm = x_mask[b * T_TEXT + i];
        swm[i] = (int)(wf * xm);      // reference truncation semantics
        sxm[i] = xm;
    }
    __syncthreads();

    // --- inclusive scan: pair-sum to 256, Hillis-Steele, expand ---
    const int wm0 = swm[2 * t];
    const int wm1 = swm[2 * t + 1];
    sp[t] = wm0 + wm1;
    for (int off = 1; off < NTHREADS; off <<= 1) {
        __syncthreads();
        int v = (t >= off) ? sp[t - off] : 0;
        __syncthreads();
        sp[t] += v;
    }
    __syncthreads();
    const int P    = sp[t];           // inclusive sum through token 2t+1
    int end1   = P;                   // cum[2t+1]
    int end0   = P - wm1;             // cum[2t]
    int start0 = end0 - wm0;

    // --- init inverse map ---
    for (int j = t; j < T_FEAT; j += NTHREADS) {
        sidx[j] = 0;
        sscale[j] = 0.0f;
    }
    __syncthreads();

    // --- scatter: each thread owns tokens 2t and 2t+1 (disjoint j ranges) ---
    {
        int s0 = min(start0, T_FEAT), e0 = min(end0, T_FEAT);
        float xm0 = sxm[2 * t];
        for (int j = s0; j < e0; ++j) { sidx[j] = (short)(2 * t);     sscale[j] = xm0; }
        int s1 = min(end0, T_FEAT),   e1 = min(end1, T_FEAT);
        float xm1 = sxm[2 * t + 1];
        for (int j = s1; j < e1; ++j) { sidx[j] = (short)(2 * t + 1); sscale[j] = xm1; }
    }
    __syncthreads();

    // --- fold y_mask into scale (vectorized, one pass) ---
    for (int j4 = t; j4 < T_FEAT / 4; j4 += NTHREADS) {
        int j = j4 * 4;
        float4 ym = *(const float4*)(y_mask + b * T_FEAT + j);
        float4 sc = *(float4*)(sscale + j);
        sc.x *= ym.x; sc.y *= ym.y; sc.z *= ym.z; sc.w *= ym.w;
        *(float4*)(sscale + j) = sc;
    }
    __syncthreads();

    // --- gather + stream out: CH_TILE channels, float4 stores ---
    for (int c0 = 0; c0 < CH_TILE; ++c0) {
        const int c = tile * CH_TILE + c0;
        const float* __restrict__ xrow = x + ((size_t)b * CC + c) * T_TEXT;
        float* __restrict__ orow = out + ((size_t)b * CC + c) * T_FEAT;
        for (int j4 = t; j4 < T_FEAT / 4; j4 += NTHREADS) {
            int j = j4 * 4;
            short4 i4 = *(const short4*)(sidx + j);
            float4 s4 = *(const float4*)(sscale + j);
            float4 o;
            o.x = xrow[i4.x] * s4.x;
            o.y = xrow[i4.y] * s4.y;
            o.z = xrow[i4.z] * s4.z;
            o.w = xrow[i4.w] * s4.w;
            *(float4*)(orow + j) = o;
        }
    }
}

extern "C" void kernel_launch(void* const* d_in, const int* in_sizes, int n_in,
                              void* d_out, int out_size, void* d_ws, size_t ws_size,
                              hipStream_t stream) {
    const float* x      = (const float*)d_in[0];
    const int*   w      = (const int*)d_in[1];
    const float* x_mask = (const float*)d_in[2];
    const float* y_mask = (const float*)d_in[3];
    float* out = (float*)d_out;

    dup_by_dur_fused<<<BB * NTILES, NTHREADS, 0, stream>>>(x, w, x_mask, y_mask, out);
}

// Round 4
// 13.299 us; speedup vs baseline: 1.3425x; 1.1788x over previous
//
#include <hip/hip_runtime.h>

// DuplicateByDuration, fused single kernel, wave-scan prologue.
// y[b,c,j] = x[b,c,i(b,j)] * x_mask[b,i] * y_mask[b,j]; i(b,j) = token whose
// cumulative-duration interval contains frame j; 0 past total duration.
// B=16, C=192, T_TEXT=512, T_FEAT=2048, w in [0,8).

#define BB 16
#define CC 192
#define T_TEXT 512
#define T_FEAT 2048
#define CH_TILE 3
#define NTILES (CC / CH_TILE)   // 64
#define NTHREADS 256
#define NWAVES (NTHREADS / 64)

__global__ __launch_bounds__(NTHREADS) void dup_by_dur_fused(
    const float* __restrict__ x, const int* __restrict__ w,
    const float* __restrict__ x_mask, const float* __restrict__ y_mask,
    float* __restrict__ out)
{
    const int t    = threadIdx.x;
    const int lane = t & 63;
    const int wv   = t >> 6;
    const int b    = blockIdx.x / NTILES;
    const int tile = blockIdx.x % NTILES;

    __shared__ int   wtot[NWAVES];
    __shared__ short sidx[T_FEAT];    // frame -> token
    __shared__ float sscale[T_FEAT];  // x_mask[i] * y_mask[j] (0 if invalid)

    // --- coalesced loads: thread t owns tokens 2t, 2t+1 ---
    const int2   w2  = *(const int2*)(w + b * T_TEXT + 2 * t);
    const float2 xm2 = *(const float2*)(x_mask + b * T_TEXT + 2 * t);
    // prefetch y_mask (latency hides under scan)
    const float4 ymA = *(const float4*)(y_mask + b * T_FEAT + 4 * t);
    const float4 ymB = *(const float4*)(y_mask + b * T_FEAT + 1024 + 4 * t);

    const int wm0 = (int)((float)w2.x * xm2.x);   // reference truncation
    const int wm1 = (int)((float)w2.y * xm2.y);

    // --- init inverse map: FULL coverage (8 shorts + 8 floats per thread) ---
    *(int4*)(sidx + 8 * t) = int4{0, 0, 0, 0};            // shorts 8t..8t+7 -> all 2048
    *(float4*)(sscale + 4 * t) = float4{0.f, 0.f, 0.f, 0.f};
    *(float4*)(sscale + 1024 + 4 * t) = float4{0.f, 0.f, 0.f, 0.f};

    // --- register wave scan of pair sums ---
    int p = wm0 + wm1;
    #pragma unroll
    for (int off = 1; off < 64; off <<= 1) {
        int v = __shfl_up(p, off);
        if (lane >= off) p += v;
    }
    if (lane == 63) wtot[wv] = p;
    __syncthreads();

    int prefix = 0;
    #pragma unroll
    for (int k = 0; k < NWAVES; ++k)
        if (k < wv) prefix += wtot[k];
    const int end1   = prefix + p;          // cum[2t+1]
    const int end0   = end1 - wm1;          // cum[2t]
    const int start0 = end0 - wm0;

    // --- scatter own tokens' frame ranges (disjoint across threads) ---
    {
        int s0 = min(start0, T_FEAT), e0 = min(end0, T_FEAT);
        for (int j = s0; j < e0; ++j) { sidx[j] = (short)(2 * t);     sscale[j] = xm2.x; }
        int s1 = e0,                  e1 = min(end1, T_FEAT);
        for (int j = s1; j < e1; ++j) { sidx[j] = (short)(2 * t + 1); sscale[j] = xm2.y; }
    }
    __syncthreads();

    // --- fold prefetched y_mask into scale ---
    {
        float4 a = *(float4*)(sscale + 4 * t);
        a.x *= ymA.x; a.y *= ymA.y; a.z *= ymA.z; a.w *= ymA.w;
        *(float4*)(sscale + 4 * t) = a;
        float4 c = *(float4*)(sscale + 1024 + 4 * t);
        c.x *= ymB.x; c.y *= ymB.y; c.z *= ymB.z; c.w *= ymB.w;
        *(float4*)(sscale + 1024 + 4 * t) = c;
    }
    __syncthreads();

    // --- gather + stream out: read map once, use for CH_TILE channels ---
    const float* __restrict__ xr0 = x + ((size_t)b * CC + tile * CH_TILE + 0) * T_TEXT;
    const float* __restrict__ xr1 = x + ((size_t)b * CC + tile * CH_TILE + 1) * T_TEXT;
    const float* __restrict__ xr2 = x + ((size_t)b * CC + tile * CH_TILE + 2) * T_TEXT;
    float* __restrict__ or0 = out + ((size_t)b * CC + tile * CH_TILE + 0) * T_FEAT;
    float* __restrict__ or1 = out + ((size_t)b * CC + tile * CH_TILE + 1) * T_FEAT;
    float* __restrict__ or2 = out + ((size_t)b * CC + tile * CH_TILE + 2) * T_FEAT;

    #pragma unroll
    for (int rep = 0; rep < T_FEAT / 4 / NTHREADS; ++rep) {
        const int j = 4 * (t + rep * NTHREADS);
        const short4 i4 = *(const short4*)(sidx + j);
        const float4 s4 = *(const float4*)(sscale + j);
        float4 o;
        o.x = xr0[i4.x] * s4.x; o.y = xr0[i4.y] * s4.y;
        o.z = xr0[i4.z] * s4.z; o.w = xr0[i4.w] * s4.w;
        *(float4*)(or0 + j) = o;
        o.x = xr1[i4.x] * s4.x; o.y = xr1[i4.y] * s4.y;
        o.z = xr1[i4.z] * s4.z; o.w = xr1[i4.w] * s4.w;
        *(float4*)(or1 + j) = o;
        o.x = xr2[i4.x] * s4.x; o.y = xr2[i4.y] * s4.y;
        o.z = xr2[i4.z] * s4.z; o.w = xr2[i4.w] * s4.w;
        *(float4*)(or2 + j) = o;
    }
}

extern "C" void kernel_launch(void* const* d_in, const int* in_sizes, int n_in,
                              void* d_out, int out_size, void* d_ws, size_t ws_size,
                              hipStream_t stream) {
    const float* x      = (const float*)d_in[0];
    const int*   w      = (const int*)d_in[1];
    const float* x_mask = (const float*)d_in[2];
    const float* y_mask = (const float*)d_in[3];
    float* out = (float*)d_out;

    dup_by_dur_fused<<<BB * NTILES, NTHREADS, 0, stream>>>(x, w, x_mask, y_mask, out);
}

// Round 5
// 13.165 us; speedup vs baseline: 1.3562x; 1.0102x over previous
//
#include <hip/hip_runtime.h>

// DuplicateByDuration, fused, fat-block version.
// y[b,c,j] = x[b,c,i(b,j)] * x_mask[b,i] * y_mask[b,j]; i(b,j) = token whose
// cumulative-duration interval contains frame j; 0 past total duration.
// B=16, C=192, T_TEXT=512, T_FEAT=2048, w in [0,8).
//
// Grid = 16 batches x 16 channel-tiles = 256 blocks of 1024 threads
// (1 block/CU, 4 waves/SIMD). Prologue (scan + inverse-map scatter) is paid
// once per CU; stream phase covers 12 channels per block.

#define BB 16
#define CC 192
#define T_TEXT 512
#define T_FEAT 2048
#define CH_TILE 12
#define NTILES (CC / CH_TILE)   // 16
#define NTHREADS 1024

__global__ __launch_bounds__(NTHREADS) void dup_by_dur_fused(
    const float* __restrict__ x, const int* __restrict__ w,
    const float* __restrict__ x_mask, const float* __restrict__ y_mask,
    float* __restrict__ out)
{
    const int t    = threadIdx.x;
    const int lane = t & 63;
    const int wv   = t >> 6;            // 0..15 (waves 0..7 own tokens)
    const int b    = blockIdx.x >> 4;
    const int tile = blockIdx.x & 15;

    __shared__ int   wtot[16];
    __shared__ short sidx[T_FEAT];      // frame -> token
    __shared__ float sxm[T_FEAT];       // x_mask[token(j)] (0 if past total)

    // --- init inverse map: each thread zeroes 2 shorts + 2 floats ---
    *(int*)(sidx + 2 * t) = 0;
    *(float2*)(sxm + 2 * t) = float2{0.f, 0.f};

    // --- one token per thread (t < 512), coalesced scalar loads ---
    int wm = 0; float xm = 0.f;
    if (t < T_TEXT) {
        float wf = (float)w[b * T_TEXT + t];
        xm = x_mask[b * T_TEXT + t];
        wm = (int)(wf * xm);            // reference truncation semantics
    }

    // --- register wave scan (waves 0..7 carry data; others scan zeros) ---
    int p = wm;
    #pragma unroll
    for (int off = 1; off < 64; off <<= 1) {
        int v = __shfl_up(p, off);
        if (lane >= off) p += v;
    }
    if (lane == 63) wtot[wv] = p;
    __syncthreads();                    // covers map init + wtot

    // --- scatter own token's frame range (disjoint across threads) ---
    if (t < T_TEXT) {
        int prefix = 0;
        #pragma unroll
        for (int k = 0; k < T_TEXT / 64; ++k)
            if (k < wv) prefix += wtot[k];
        int end   = prefix + p;         // cum[t]
        int start = end - wm;
        start = min(start, T_FEAT);
        end   = min(end, T_FEAT);
        for (int j = start; j < end; ++j) { sidx[j] = (short)t; sxm[j] = xm; }
    }
    __syncthreads();

    // --- stream: each thread owns one float4 j-group for 6 channels ---
    const int j  = 4 * (t & 511);
    const int ch = t >> 9;              // 0 or 1
    const short4 i4 = *(const short4*)(sidx + j);
    float4 s4 = *(const float4*)(sxm + j);
    const float4 ym = *(const float4*)(y_mask + (size_t)b * T_FEAT + j);
    s4.x *= ym.x; s4.y *= ym.y; s4.z *= ym.z; s4.w *= ym.w;

    const int cbase = tile * CH_TILE + ch;
    #pragma unroll
    for (int k = 0; k < CH_TILE / 2; ++k) {
        const int c = cbase + 2 * k;
        const float* __restrict__ xr = x + ((size_t)b * CC + c) * T_TEXT;
        float* __restrict__ orow = out + ((size_t)b * CC + c) * T_FEAT;
        float4 o;
        o.x = xr[i4.x] * s4.x;
        o.y = xr[i4.y] * s4.y;
        o.z = xr[i4.z] * s4.z;
        o.w = xr[i4.w] * s4.w;
        *(float4*)(orow + j) = o;
    }
}

extern "C" void kernel_launch(void* const* d_in, const int* in_sizes, int n_in,
                              void* d_out, int out_size, void* d_ws, size_t ws_size,
                              hipStream_t stream) {
    const float* x      = (const float*)d_in[0];
    const int*   w      = (const int*)d_in[1];
    const float* x_mask = (const float*)d_in[2];
    const float* y_mask = (const float*)d_in[3];
    float* out = (float*)d_out;

    dup_by_dur_fused<<<BB * NTILES, NTHREADS, 0, stream>>>(x, w, x_mask, y_mask, out);
}